// Round 8
// baseline (297.749 us; speedup 1.0000x reference)
//
#include <hip/hip_runtime.h>
#include <hip/hip_bf16.h>

#define NUMH 16
#define HD   64
#define EMB  1024
#define SEQL 2048
#define BATCH 4

typedef __attribute__((ext_vector_type(8))) short bf16x8;
typedef __attribute__((ext_vector_type(4))) float f32x4;
typedef __attribute__((ext_vector_type(16))) float f32x16;

__device__ __forceinline__ unsigned short f2bf(float f) {
  union { float f; unsigned int u; } v; v.f = f;
  unsigned int u = v.u + 0x7fffu + ((v.u >> 16) & 1u);
  return (unsigned short)(u >> 16);
}

__device__ __forceinline__ unsigned int cvtpk(float lo, float hi) {
  unsigned int r;
  asm("v_cvt_pk_bf16_f32 %0, %1, %2" : "=v"(r) : "v"(lo), "v"(hi));
  return r;
}

// cross-half (lane ^ 32) merge. Builtin permlane32_swap returns BOTH result
// registers; max/sum of the pair is correct under either half-pairing
// convention of the HW instruction (and has no register-aliasing hazard).
__device__ __forceinline__ float xhalf_max(float x) {
#if __has_builtin(__builtin_amdgcn_permlane32_swap)
  auto r = __builtin_amdgcn_permlane32_swap(__float_as_uint(x), __float_as_uint(x), false, false);
  return fmaxf(__uint_as_float(r[0]), __uint_as_float(r[1]));
#else
  return fmaxf(x, __shfl_xor(x, 32));
#endif
}
__device__ __forceinline__ float xhalf_sum(float x) {
#if __has_builtin(__builtin_amdgcn_permlane32_swap)
  auto r = __builtin_amdgcn_permlane32_swap(__float_as_uint(x), __float_as_uint(x), false, false);
  return __uint_as_float(r[0]) + __uint_as_float(r[1]);
#else
  return x + __shfl_xor(x, 32);
#endif
}

#define GLOAD16(gp, lp)                                                        \
  __builtin_amdgcn_global_load_lds(                                            \
      (const __attribute__((address_space(1))) unsigned int*)(gp),             \
      (__attribute__((address_space(3))) unsigned int*)(lp), 16, 0, 0)

// ---------- convert x fp32 -> bf16 ----------
__global__ __launch_bounds__(256) void cvt_x(const float* __restrict__ src,
                                             unsigned short* __restrict__ dst) {
  const size_t i = ((size_t)blockIdx.x * 256 + threadIdx.x) * 8;
  float4 a = *(const float4*)(src + i);
  float4 b = *(const float4*)(src + i + 4);
  bf16x8 w;
  w[0]=(short)f2bf(a.x); w[1]=(short)f2bf(a.y); w[2]=(short)f2bf(a.z); w[3]=(short)f2bf(a.w);
  w[4]=(short)f2bf(b.x); w[5]=(short)f2bf(b.y); w[6]=(short)f2bf(b.z); w[7]=(short)f2bf(b.w);
  *(bf16x8*)(dst + i) = w;
}

// ---------- transpose + convert: src[R][C] fp32 -> dst[C][R] bf16 ----------
__global__ __launch_bounds__(256) void tr_cvt(const float* __restrict__ src,
                                              unsigned short* __restrict__ dst,
                                              int R, int C) {
  __shared__ unsigned short t[32][34];
  const int tx = threadIdx.x & 31, ty = threadIdx.x >> 5;
  const int c0 = blockIdx.x * 32, r0 = blockIdx.y * 32;
#pragma unroll
  for (int i = 0; i < 4; ++i)
    t[ty + i * 8][tx] = f2bf(src[(size_t)(r0 + ty + i * 8) * C + c0 + tx]);
  __syncthreads();
#pragma unroll
  for (int i = 0; i < 4; ++i)
    dst[(size_t)(c0 + ty + i * 8) * R + r0 + tx] = t[tx][ty + i * 8];
}

// ---------- m97-style GEMM: A[M][1024] bf16, BT[N][1024] bf16 ----------
__global__ __launch_bounds__(256, 3) void gemm_qkv(
    const unsigned short* __restrict__ A, const unsigned short* __restrict__ BT,
    const float* __restrict__ Bias,
    unsigned short* __restrict__ Qo, unsigned short* __restrict__ Ko,
    unsigned short* __restrict__ Vo) {
  __shared__ __align__(16) unsigned short As[128][32];
  __shared__ __align__(16) unsigned short Bs[128][32];
  const int tid = threadIdx.x, lane = tid & 63, wv = tid >> 6;
  const int l15 = lane & 15, lg = lane >> 4;
  const int wrow = (wv >> 1) * 64, wcol = (wv & 1) * 64;
  const int cpx = gridDim.x >> 3;
  const int wg = (blockIdx.x & 7) * cpx + (blockIdx.x >> 3);
  const int mbase = (wg / 24) * 128, nbase = (wg % 24) * 128;

  f32x4 acc[4][4];
#pragma unroll
  for (int i = 0; i < 4; ++i)
#pragma unroll
    for (int j = 0; j < 4; ++j) acc[i][j] = (f32x4){0.f, 0.f, 0.f, 0.f};

  const int c0 = wv * 64 + lane;
  const unsigned short* ga0 = A + (size_t)(mbase + (c0 >> 2)) * EMB + (c0 & 3) * 8;
  const unsigned short* ga1 = ga0 + (size_t)64 * EMB;
  const unsigned short* gb0 = BT + (size_t)(nbase + (c0 >> 2)) * EMB + (c0 & 3) * 8;
  const unsigned short* gb1 = gb0 + (size_t)64 * EMB;
  unsigned short* la0 = &As[0][0] + c0 * 8;
  unsigned short* lb0 = &Bs[0][0] + c0 * 8;

  for (int k0 = 0; k0 < EMB; k0 += 32) {
    __syncthreads();
    GLOAD16(ga0 + k0, la0);
    GLOAD16(ga1 + k0, la0 + 2048);
    GLOAD16(gb0 + k0, lb0);
    GLOAD16(gb1 + k0, lb0 + 2048);
    __syncthreads();
    bf16x8 af[4], bfr[4];
#pragma unroll
    for (int mf = 0; mf < 4; ++mf)
      af[mf] = *(const bf16x8*)&As[wrow + mf * 16 + l15][lg * 8];
#pragma unroll
    for (int nf = 0; nf < 4; ++nf)
      bfr[nf] = *(const bf16x8*)&Bs[wcol + nf * 16 + l15][lg * 8];
#pragma unroll
    for (int mf = 0; mf < 4; ++mf)
#pragma unroll
      for (int nf = 0; nf < 4; ++nf)
        acc[mf][nf] = __builtin_amdgcn_mfma_f32_16x16x32_bf16(af[mf], bfr[nf], acc[mf][nf], 0, 0, 0);
  }

#pragma unroll
  for (int nf = 0; nf < 4; ++nf) {
    const int n = nbase + wcol + nf * 16 + l15;
    const float bias = Bias[n];
    const int which = n >> 10, rem = n & 1023;
    const int h = rem >> 6, d = rem & 63;
    unsigned short* dst = (which == 0) ? Qo : (which == 1) ? Ko : Vo;
#pragma unroll
    for (int mf = 0; mf < 4; ++mf)
#pragma unroll
      for (int j = 0; j < 4; ++j) {
        const int m = mbase + wrow + mf * 16 + lg * 4 + j;
        const int bb = m >> 11, s = m & 2047;
        dst[((size_t)(bb * NUMH + h) * SEQL + s) * HD + d] = f2bf(acc[mf][nf][j] + bias);
      }
  }
}

__global__ __launch_bounds__(256, 3) void gemm_out(
    const unsigned short* __restrict__ A, const unsigned short* __restrict__ BT,
    const float* __restrict__ Bias, float* __restrict__ Out) {
  __shared__ __align__(16) unsigned short As[128][32];
  __shared__ __align__(16) unsigned short Bs[128][32];
  const int tid = threadIdx.x, lane = tid & 63, wv = tid >> 6;
  const int l15 = lane & 15, lg = lane >> 4;
  const int wrow = (wv >> 1) * 64, wcol = (wv & 1) * 64;
  const int cpx = gridDim.x >> 3;
  const int wg = (blockIdx.x & 7) * cpx + (blockIdx.x >> 3);
  const int mbase = (wg >> 3) * 128, nbase = (wg & 7) * 128;

  f32x4 acc[4][4];
#pragma unroll
  for (int i = 0; i < 4; ++i)
#pragma unroll
    for (int j = 0; j < 4; ++j) acc[i][j] = (f32x4){0.f, 0.f, 0.f, 0.f};

  const int c0 = wv * 64 + lane;
  const unsigned short* ga0 = A + (size_t)(mbase + (c0 >> 2)) * EMB + (c0 & 3) * 8;
  const unsigned short* ga1 = ga0 + (size_t)64 * EMB;
  const unsigned short* gb0 = BT + (size_t)(nbase + (c0 >> 2)) * EMB + (c0 & 3) * 8;
  const unsigned short* gb1 = gb0 + (size_t)64 * EMB;
  unsigned short* la0 = &As[0][0] + c0 * 8;
  unsigned short* lb0 = &Bs[0][0] + c0 * 8;

  for (int k0 = 0; k0 < EMB; k0 += 32) {
    __syncthreads();
    GLOAD16(ga0 + k0, la0);
    GLOAD16(ga1 + k0, la0 + 2048);
    GLOAD16(gb0 + k0, lb0);
    GLOAD16(gb1 + k0, lb0 + 2048);
    __syncthreads();
    bf16x8 af[4], bfr[4];
#pragma unroll
    for (int mf = 0; mf < 4; ++mf)
      af[mf] = *(const bf16x8*)&As[wrow + mf * 16 + l15][lg * 8];
#pragma unroll
    for (int nf = 0; nf < 4; ++nf)
      bfr[nf] = *(const bf16x8*)&Bs[wcol + nf * 16 + l15][lg * 8];
#pragma unroll
    for (int mf = 0; mf < 4; ++mf)
#pragma unroll
      for (int nf = 0; nf < 4; ++nf)
        acc[mf][nf] = __builtin_amdgcn_mfma_f32_16x16x32_bf16(af[mf], bfr[nf], acc[mf][nf], 0, 0, 0);
  }

#pragma unroll
  for (int nf = 0; nf < 4; ++nf) {
    const int n = nbase + wcol + nf * 16 + l15;
    const float bias = Bias[n];
#pragma unroll
    for (int mf = 0; mf < 4; ++mf)
#pragma unroll
      for (int j = 0; j < 4; ++j) {
        const int m = mbase + wrow + mf * 16 + lg * 4 + j;
        Out[(size_t)m * EMB + n] = acc[mf][nf][j] + bias;
      }
  }
}

// ---- softmax + P-pack for one 32q x 64kv S^T block (lane owns q = lane&31) ----
// P-pack uses R3's verified shfl_xor(32) + hi-select construction.
__device__ __forceinline__ void sm_pack(f32x16& S0, f32x16& S1, float& MR, float& LR,
                                        f32x16& O0, f32x16& O1, bf16x8 Pf[4],
                                        int ktb, int qrow, int q0w, int hi) {
  const float AS = 0.18033688011112042f;  // 0.125 * log2(e)
  const float THRR = 44.36f;              // 8 / AS (defer-max threshold, raw)
  if (ktb + 63 > q0w) {  // causal mask, near-diag tiles only
#pragma unroll
    for (int r = 0; r < 16; ++r) {
      const int kv0 = ktb + (r & 3) + 8 * (r >> 2) + 4 * hi;
      S0[r] = (kv0 > qrow) ? -1e30f : S0[r];
      S1[r] = (kv0 + 32 > qrow) ? -1e30f : S1[r];
    }
  }
  float t[16];
#pragma unroll
  for (int i = 0; i < 16; ++i) t[i] = fmaxf(S0[i], S1[i]);
#pragma unroll
  for (int i = 0; i < 8; ++i) t[i] = fmaxf(t[i], t[i + 8]);
#pragma unroll
  for (int i = 0; i < 4; ++i) t[i] = fmaxf(t[i], t[i + 4]);
  float mx = fmaxf(fmaxf(t[0], t[1]), fmaxf(t[2], t[3]));
  mx = xhalf_max(mx);
  if (!__all(mx - MR <= THRR)) {  // T13: rescale only when max grew materially
    const float mn = fmaxf(MR, mx);
    const float sc = exp2f((MR - mn) * AS);
    MR = mn;
    LR *= sc;
#pragma unroll
    for (int i = 0; i < 16; ++i) { O0[i] *= sc; O1[i] *= sc; }
  }
  const float mk = MR * AS;
#pragma unroll
  for (int i = 0; i < 16; ++i) {
    S0[i] = exp2f(__builtin_fmaf(S0[i], AS, -mk));
    S1[i] = exp2f(__builtin_fmaf(S1[i], AS, -mk));
  }
  float a[16];
#pragma unroll
  for (int i = 0; i < 16; ++i) a[i] = S0[i] + S1[i];
#pragma unroll
  for (int i = 0; i < 8; ++i) a[i] += a[i + 8];
#pragma unroll
  for (int i = 0; i < 4; ++i) a[i] += a[i + 4];
  LR += xhalf_sum((a[0] + a[1]) + (a[2] + a[3]));
  // ---- P -> bf16 dwords; exchange halves (verified R3 pattern) ----
  unsigned int W[2][4][2], X[2][4][2];
#pragma unroll
  for (int g = 0; g < 4; ++g)
#pragma unroll
    for (int c = 0; c < 2; ++c) {
      W[0][g][c] = cvtpk(S0[4 * g + 2 * c], S0[4 * g + 2 * c + 1]);
      W[1][g][c] = cvtpk(S1[4 * g + 2 * c], S1[4 * g + 2 * c + 1]);
    }
#pragma unroll
  for (int tt = 0; tt < 2; ++tt)
#pragma unroll
    for (int g = 0; g < 4; ++g)
#pragma unroll
      for (int c = 0; c < 2; ++c) X[tt][g][c] = __shfl_xor(W[tt][g][c], 32);

#pragma unroll
  for (int ks = 0; ks < 4; ++ks) {
    const int tt = ks >> 1, k1 = ks & 1;
    union { unsigned int d[4]; bf16x8 v; } u;
    u.d[0] = hi ? X[tt][2 * k1 + 1][0] : W[tt][2 * k1][0];
    u.d[1] = hi ? X[tt][2 * k1 + 1][1] : W[tt][2 * k1][1];
    u.d[2] = hi ? W[tt][2 * k1 + 1][0] : X[tt][2 * k1][0];
    u.d[3] = hi ? W[tt][2 * k1 + 1][1] : X[tt][2 * k1][1];
    Pf[ks] = u.v;
  }
}

__device__ __forceinline__ void write_o(unsigned short* Op, const f32x16& O0,
                                        const f32x16& O1, float LR, int hi) {
  const float inv = 1.0f / LR;
#pragma unroll
  for (int g = 0; g < 4; ++g) {
    unsigned int w00 = cvtpk(O0[4 * g] * inv, O0[4 * g + 1] * inv);
    unsigned int w01 = cvtpk(O0[4 * g + 2] * inv, O0[4 * g + 3] * inv);
    unsigned int w10 = cvtpk(O1[4 * g] * inv, O1[4 * g + 1] * inv);
    unsigned int w11 = cvtpk(O1[4 * g + 2] * inv, O1[4 * g + 3] * inv);
    const int dd = 8 * g + 4 * hi;
    *(uint2*)&Op[dd]      = uint2{w00, w01};
    *(uint2*)&Op[32 + dd] = uint2{w10, w11};
  }
}

// ---------------- causal flash attention, fused dual-tile ------------------
// 512 blocks; block handles q-tiles A=qp, B=15-qp in ONE kv loop (dual state
// per wave). K/V staged once per kv tile; LDS frags shared by both tiles.
__global__ __launch_bounds__(256, 2) void attn_fwd(
    const unsigned short* __restrict__ Q, const unsigned short* __restrict__ K,
    const unsigned short* __restrict__ V, unsigned short* __restrict__ O) {
  __shared__ __align__(16) unsigned short Ks[64][72];  // [kv][hd]
  __shared__ __align__(16) unsigned short VT[64][72];  // [hd][kv]
  const int tid = threadIdx.x, lane = tid & 63, wv = tid >> 6;
  const int l31 = lane & 31, hi = lane >> 5;
  const int d0 = blockIdx.x;
  const int qp = (d0 >> 3) & 7;
  const int bh = ((d0 & 7) << 3) | (d0 >> 6);
  const int b = bh >> 4, h = bh & 15;
  const size_t bho = (size_t)(b * NUMH + h) * SEQL * HD;
  const unsigned short* Qb = Q + bho;
  const unsigned short* Kb = K + bho;
  const unsigned short* Vb = V + bho;

  const int qtA = qp, qtB = 15 - qp;
  const int q0wA = qtA * 128 + wv * 32, q0wB = qtB * 128 + wv * 32;
  const int qrowA = q0wA + l31, qrowB = q0wB + l31;

  const int skrow = tid >> 2, skcol = (tid & 3) * 16;
  const int svrow = tid & 63, svd = (tid >> 6) * 16;

  bf16x8 qfA[4], qfB[4];
#pragma unroll
  for (int s = 0; s < 4; ++s) {
    qfA[s] = *(const bf16x8*)&Qb[(size_t)qrowA * HD + s * 16 + hi * 8];
    qfB[s] = *(const bf16x8*)&Qb[(size_t)qrowB * HD + s * 16 + hi * 8];
  }

  f32x16 OA0, OA1, OB0, OB1;
#pragma unroll
  for (int i = 0; i < 16; ++i) { OA0[i] = 0.f; OA1[i] = 0.f; OB0[i] = 0.f; OB1[i] = 0.f; }
  float mA = -1e30f, lA = 0.f, mB = -1e30f, lB = 0.f;

  const int nkt = 2 * qtB + 2;
  for (int kt = 0; kt < nkt; ++kt) {
    const int ktb = kt * 64;
    __syncthreads();
    {  // stage K [64][64] -> Ks
      const unsigned short* kp = &Kb[(size_t)(ktb + skrow) * HD + skcol];
      *(uint4*)&Ks[skrow][skcol] = *(const uint4*)kp;
      *(uint4*)&Ks[skrow][skcol + 8] = *(const uint4*)(kp + 8);
    }
    {  // stage V transposed -> VT[d][kv]
      const unsigned short* vp = &Vb[(size_t)(ktb + svrow) * HD + svd];
      union { uint4 u[2]; unsigned short s[16]; } vb;
      vb.u[0] = *(const uint4*)vp;
      vb.u[1] = *(const uint4*)(vp + 8);
#pragma unroll
      for (int i = 0; i < 16; ++i) VT[svd + i][svrow] = vb.s[i];
    }
    __syncthreads();

    const bool aAct = (ktb <= q0wA + 31);   // wave-uniform
    const bool bAct = (ktb <= q0wB + 31);   // wave-uniform

    f32x16 SA0, SA1, SB0, SB1;
    if (bAct) {
#pragma unroll
      for (int i = 0; i < 16; ++i) { SB0[i] = 0.f; SB1[i] = 0.f; }
    }
    if (aAct) {
#pragma unroll
      for (int i = 0; i < 16; ++i) { SA0[i] = 0.f; SA1[i] = 0.f; }
    }
#pragma unroll
    for (int s = 0; s < 4; ++s) {
      bf16x8 kf0 = *(const bf16x8*)&Ks[l31][s * 16 + hi * 8];
      bf16x8 kf1 = *(const bf16x8*)&Ks[32 + l31][s * 16 + hi * 8];
      if (bAct) {
        SB0 = __builtin_amdgcn_mfma_f32_32x32x16_bf16(kf0, qfB[s], SB0, 0, 0, 0);
        SB1 = __builtin_amdgcn_mfma_f32_32x32x16_bf16(kf1, qfB[s], SB1, 0, 0, 0);
      }
      if (aAct) {
        SA0 = __builtin_amdgcn_mfma_f32_32x32x16_bf16(kf0, qfA[s], SA0, 0, 0, 0);
        SA1 = __builtin_amdgcn_mfma_f32_32x32x16_bf16(kf1, qfA[s], SA1, 0, 0, 0);
      }
    }

    bf16x8 PfA[4], PfB[4];
    if (aAct) sm_pack(SA0, SA1, mA, lA, OA0, OA1, PfA, ktb, qrowA, q0wA, hi);
    if (bAct) sm_pack(SB0, SB1, mB, lB, OB0, OB1, PfB, ktb, qrowB, q0wB, hi);

#pragma unroll
    for (int ks = 0; ks < 4; ++ks) {
      bf16x8 vf0 = *(const bf16x8*)&VT[l31][ks * 16 + hi * 8];
      bf16x8 vf1 = *(const bf16x8*)&VT[32 + l31][ks * 16 + hi * 8];
      if (bAct) {
        OB0 = __builtin_amdgcn_mfma_f32_32x32x16_bf16(vf0, PfB[ks], OB0, 0, 0, 0);
        OB1 = __builtin_amdgcn_mfma_f32_32x32x16_bf16(vf1, PfB[ks], OB1, 0, 0, 0);
      }
      if (aAct) {
        OA0 = __builtin_amdgcn_mfma_f32_32x32x16_bf16(vf0, PfA[ks], OA0, 0, 0, 0);
        OA1 = __builtin_amdgcn_mfma_f32_32x32x16_bf16(vf1, PfA[ks], OA1, 0, 0, 0);
      }
    }
  }

  write_o(O + ((size_t)b * SEQL + qrowA) * EMB + h * HD, OA0, OA1, lA, hi);
  write_o(O + ((size_t)b * SEQL + qrowB) * EMB + h * HD, OB0, OB1, lB, hi);
}

extern "C" void kernel_launch(void* const* d_in, const int* in_sizes, int n_in,
                              void* d_out, int out_size, void* d_ws, size_t ws_size,
                              hipStream_t stream) {
  const float* x     = (const float*)d_in[0];
  const float* w_qkv = (const float*)d_in[1];
  const float* b_qkv = (const float*)d_in[2];
  const float* w_out = (const float*)d_in[3];
  const float* b_out = (const float*)d_in[4];
  float* out = (float*)d_out;

  const size_t NE = (size_t)BATCH * NUMH * SEQL * HD;  // 8,388,608
  unsigned short* Qb = (unsigned short*)d_ws;
  unsigned short* Kb = Qb + NE;
  unsigned short* Vb = Kb + NE;
  unsigned short* AO = Vb + NE;
  unsigned short* xb = AO + NE;
  unsigned short* wqkvT = xb + NE;              // [3072][1024]
  unsigned short* woutT = wqkvT + 3072 * 1024;  // [1024][1024]

  cvt_x<<<dim3((unsigned)(NE / (256 * 8))), 256, 0, stream>>>(x, xb);
  tr_cvt<<<dim3(3072 / 32, 1024 / 32), 256, 0, stream>>>(w_qkv, wqkvT, 1024, 3072);
  tr_cvt<<<dim3(1024 / 32, 1024 / 32), 256, 0, stream>>>(w_out, woutT, 1024, 1024);

  gemm_qkv<<<dim3(1536), 256, 0, stream>>>(xb, wqkvT, b_qkv, Qb, Kb, Vb);
  attn_fwd<<<dim3(512), 256, 0, stream>>>(Qb, Kb, Vb, AO);
  gemm_out<<<dim3(512), 256, 0, stream>>>(AO, woutT, b_out, out);
}

// Round 9
// 263.017 us; speedup vs baseline: 1.1321x; 1.1321x over previous
//
#include <hip/hip_runtime.h>
#include <hip/hip_bf16.h>

#define NUMH 16
#define HD   64
#define EMB  1024
#define SEQL 2048
#define BATCH 4

typedef __attribute__((ext_vector_type(8))) short bf16x8;
typedef __attribute__((ext_vector_type(4))) float f32x4;
typedef __attribute__((ext_vector_type(16))) float f32x16;

__device__ __forceinline__ unsigned short f2bf(float f) {
  union { float f; unsigned int u; } v; v.f = f;
  unsigned int u = v.u + 0x7fffu + ((v.u >> 16) & 1u);
  return (unsigned short)(u >> 16);
}

__device__ __forceinline__ unsigned int cvtpk(float lo, float hi) {
  unsigned int r;
  asm("v_cvt_pk_bf16_f32 %0, %1, %2" : "=v"(r) : "v"(lo), "v"(hi));
  return r;
}

// cross-half (lane ^ 32) merge — VERIFIED on HW in R8 (absmax 0.0156).
__device__ __forceinline__ float xhalf_max(float x) {
#if __has_builtin(__builtin_amdgcn_permlane32_swap)
  auto r = __builtin_amdgcn_permlane32_swap(__float_as_uint(x), __float_as_uint(x), false, false);
  return fmaxf(__uint_as_float(r[0]), __uint_as_float(r[1]));
#else
  return fmaxf(x, __shfl_xor(x, 32));
#endif
}
__device__ __forceinline__ float xhalf_sum(float x) {
#if __has_builtin(__builtin_amdgcn_permlane32_swap)
  auto r = __builtin_amdgcn_permlane32_swap(__float_as_uint(x), __float_as_uint(x), false, false);
  return __uint_as_float(r[0]) + __uint_as_float(r[1]);
#else
  return x + __shfl_xor(x, 32);
#endif
}

#define GLOAD16(gp, lp)                                                        \
  __builtin_amdgcn_global_load_lds(                                            \
      (const __attribute__((address_space(1))) unsigned int*)(gp),             \
      (__attribute__((address_space(3))) unsigned int*)(lp), 16, 0, 0)

// ---------- convert x fp32 -> bf16 ----------
__global__ __launch_bounds__(256) void cvt_x(const float* __restrict__ src,
                                             unsigned short* __restrict__ dst) {
  const size_t i = ((size_t)blockIdx.x * 256 + threadIdx.x) * 8;
  float4 a = *(const float4*)(src + i);
  float4 b = *(const float4*)(src + i + 4);
  bf16x8 w;
  w[0]=(short)f2bf(a.x); w[1]=(short)f2bf(a.y); w[2]=(short)f2bf(a.z); w[3]=(short)f2bf(a.w);
  w[4]=(short)f2bf(b.x); w[5]=(short)f2bf(b.y); w[6]=(short)f2bf(b.z); w[7]=(short)f2bf(b.w);
  *(bf16x8*)(dst + i) = w;
}

// ---------- transpose + convert: src[R][C] fp32 -> dst[C][R] bf16 ----------
__global__ __launch_bounds__(256) void tr_cvt(const float* __restrict__ src,
                                              unsigned short* __restrict__ dst,
                                              int R, int C) {
  __shared__ unsigned short t[32][34];
  const int tx = threadIdx.x & 31, ty = threadIdx.x >> 5;
  const int c0 = blockIdx.x * 32, r0 = blockIdx.y * 32;
#pragma unroll
  for (int i = 0; i < 4; ++i)
    t[ty + i * 8][tx] = f2bf(src[(size_t)(r0 + ty + i * 8) * C + c0 + tx]);
  __syncthreads();
#pragma unroll
  for (int i = 0; i < 4; ++i)
    dst[(size_t)(c0 + ty + i * 8) * R + r0 + tx] = t[tx][ty + i * 8];
}

// ---------- GEMM, BK=64 + XOR-swizzled LDS (pre-swizzled global source) ----
// LDS[row][cc*8..] holds orig[row][(cc^(row&7))*8..]; read applies same XOR.
// Halves barrier-drains per MFMA vs BK=32; swizzle keeps ds_read ~2-way.
__global__ __launch_bounds__(256, 3) void gemm_qkv(
    const unsigned short* __restrict__ A, const unsigned short* __restrict__ BT,
    const float* __restrict__ Bias,
    unsigned short* __restrict__ Qo, unsigned short* __restrict__ Ko,
    unsigned short* __restrict__ Vo) {
  __shared__ __align__(16) unsigned short As[128][64];
  __shared__ __align__(16) unsigned short Bs[128][64];
  const int tid = threadIdx.x, lane = tid & 63, wv = tid >> 6;
  const int l15 = lane & 15, lg = lane >> 4;
  const int wrow = (wv >> 1) * 64, wcol = (wv & 1) * 64;
  const int cpx = gridDim.x >> 3;
  const int wg = (blockIdx.x & 7) * cpx + (blockIdx.x >> 3);
  const int mbase = (wg / 24) * 128, nbase = (wg % 24) * 128;

  f32x4 acc[4][4];
#pragma unroll
  for (int i = 0; i < 4; ++i)
#pragma unroll
    for (int j = 0; j < 4; ++j) acc[i][j] = (f32x4){0.f, 0.f, 0.f, 0.f};

  // staging: chunk q = tid + 256*i; row = (tid>>3)+32*i; cc = tid&7 (const);
  // swizzled source column chunk scc = cc ^ (row&7) = (tid&7)^((tid>>3)&7).
  const int row0 = tid >> 3;
  const int scc = (tid & 7) ^ (row0 & 7);
  const unsigned short* gA0 = A + (size_t)(mbase + row0) * EMB + scc * 8;
  const unsigned short* gB0 = BT + (size_t)(nbase + row0) * EMB + scc * 8;
  unsigned short* lA0 = &As[0][0] + tid * 8;
  unsigned short* lB0 = &Bs[0][0] + tid * 8;

  for (int k0 = 0; k0 < EMB; k0 += 64) {
    __syncthreads();
#pragma unroll
    for (int i = 0; i < 4; ++i) {
      GLOAD16(gA0 + (size_t)(32 * i) * EMB + k0, lA0 + 2048 * i);
      GLOAD16(gB0 + (size_t)(32 * i) * EMB + k0, lB0 + 2048 * i);
    }
    __syncthreads();
#pragma unroll
    for (int ks2 = 0; ks2 < 2; ++ks2) {
      bf16x8 af[4], bfr[4];
      const int cc = ((ks2 * 4 + lg) ^ (l15 & 7)) * 8;  // row&7 == l15&7
#pragma unroll
      for (int mf = 0; mf < 4; ++mf)
        af[mf] = *(const bf16x8*)&As[wrow + mf * 16 + l15][cc];
#pragma unroll
      for (int nf = 0; nf < 4; ++nf)
        bfr[nf] = *(const bf16x8*)&Bs[wcol + nf * 16 + l15][cc];
#pragma unroll
      for (int mf = 0; mf < 4; ++mf)
#pragma unroll
        for (int nf = 0; nf < 4; ++nf)
          acc[mf][nf] = __builtin_amdgcn_mfma_f32_16x16x32_bf16(af[mf], bfr[nf], acc[mf][nf], 0, 0, 0);
    }
  }

#pragma unroll
  for (int nf = 0; nf < 4; ++nf) {
    const int n = nbase + wcol + nf * 16 + l15;
    const float bias = Bias[n];
    const int which = n >> 10, rem = n & 1023;
    const int h = rem >> 6, d = rem & 63;
    unsigned short* dst = (which == 0) ? Qo : (which == 1) ? Ko : Vo;
#pragma unroll
    for (int mf = 0; mf < 4; ++mf)
#pragma unroll
      for (int j = 0; j < 4; ++j) {
        const int m = mbase + wrow + mf * 16 + lg * 4 + j;
        const int bb = m >> 11, s = m & 2047;
        dst[((size_t)(bb * NUMH + h) * SEQL + s) * HD + d] = f2bf(acc[mf][nf][j] + bias);
      }
  }
}

__global__ __launch_bounds__(256, 3) void gemm_out(
    const unsigned short* __restrict__ A, const unsigned short* __restrict__ BT,
    const float* __restrict__ Bias, float* __restrict__ Out) {
  __shared__ __align__(16) unsigned short As[128][64];
  __shared__ __align__(16) unsigned short Bs[128][64];
  const int tid = threadIdx.x, lane = tid & 63, wv = tid >> 6;
  const int l15 = lane & 15, lg = lane >> 4;
  const int wrow = (wv >> 1) * 64, wcol = (wv & 1) * 64;
  const int cpx = gridDim.x >> 3;
  const int wg = (blockIdx.x & 7) * cpx + (blockIdx.x >> 3);
  const int mbase = (wg >> 3) * 128, nbase = (wg & 7) * 128;

  f32x4 acc[4][4];
#pragma unroll
  for (int i = 0; i < 4; ++i)
#pragma unroll
    for (int j = 0; j < 4; ++j) acc[i][j] = (f32x4){0.f, 0.f, 0.f, 0.f};

  const int row0 = tid >> 3;
  const int scc = (tid & 7) ^ (row0 & 7);
  const unsigned short* gA0 = A + (size_t)(mbase + row0) * EMB + scc * 8;
  const unsigned short* gB0 = BT + (size_t)(nbase + row0) * EMB + scc * 8;
  unsigned short* lA0 = &As[0][0] + tid * 8;
  unsigned short* lB0 = &Bs[0][0] + tid * 8;

  for (int k0 = 0; k0 < EMB; k0 += 64) {
    __syncthreads();
#pragma unroll
    for (int i = 0; i < 4; ++i) {
      GLOAD16(gA0 + (size_t)(32 * i) * EMB + k0, lA0 + 2048 * i);
      GLOAD16(gB0 + (size_t)(32 * i) * EMB + k0, lB0 + 2048 * i);
    }
    __syncthreads();
#pragma unroll
    for (int ks2 = 0; ks2 < 2; ++ks2) {
      bf16x8 af[4], bfr[4];
      const int cc = ((ks2 * 4 + lg) ^ (l15 & 7)) * 8;
#pragma unroll
      for (int mf = 0; mf < 4; ++mf)
        af[mf] = *(const bf16x8*)&As[wrow + mf * 16 + l15][cc];
#pragma unroll
      for (int nf = 0; nf < 4; ++nf)
        bfr[nf] = *(const bf16x8*)&Bs[wcol + nf * 16 + l15][cc];
#pragma unroll
      for (int mf = 0; mf < 4; ++mf)
#pragma unroll
        for (int nf = 0; nf < 4; ++nf)
          acc[mf][nf] = __builtin_amdgcn_mfma_f32_16x16x32_bf16(af[mf], bfr[nf], acc[mf][nf], 0, 0, 0);
    }
  }

#pragma unroll
  for (int nf = 0; nf < 4; ++nf) {
    const int n = nbase + wcol + nf * 16 + l15;
    const float bias = Bias[n];
#pragma unroll
    for (int mf = 0; mf < 4; ++mf)
#pragma unroll
      for (int j = 0; j < 4; ++j) {
        const int m = mbase + wrow + mf * 16 + lg * 4 + j;
        Out[(size_t)m * EMB + n] = acc[mf][nf][j] + bias;
      }
  }
}

// ---- softmax + P-pack (R8-VERIFIED: defer-max + builtin merges + shfl pack) ----
__device__ __forceinline__ void sm_pack(f32x16& S0, f32x16& S1, float& MR, float& LR,
                                        f32x16& O0, f32x16& O1, bf16x8 Pf[4],
                                        int ktb, int qrow, int q0w, int hi) {
  const float AS = 0.18033688011112042f;  // 0.125 * log2(e)
  const float THRR = 44.36f;              // 8 / AS
  if (ktb + 63 > q0w) {
#pragma unroll
    for (int r = 0; r < 16; ++r) {
      const int kv0 = ktb + (r & 3) + 8 * (r >> 2) + 4 * hi;
      S0[r] = (kv0 > qrow) ? -1e30f : S0[r];
      S1[r] = (kv0 + 32 > qrow) ? -1e30f : S1[r];
    }
  }
  float t[16];
#pragma unroll
  for (int i = 0; i < 16; ++i) t[i] = fmaxf(S0[i], S1[i]);
#pragma unroll
  for (int i = 0; i < 8; ++i) t[i] = fmaxf(t[i], t[i + 8]);
#pragma unroll
  for (int i = 0; i < 4; ++i) t[i] = fmaxf(t[i], t[i + 4]);
  float mx = fmaxf(fmaxf(t[0], t[1]), fmaxf(t[2], t[3]));
  mx = xhalf_max(mx);
  if (!__all(mx - MR <= THRR)) {
    const float mn = fmaxf(MR, mx);
    const float sc = exp2f((MR - mn) * AS);
    MR = mn;
    LR *= sc;
#pragma unroll
    for (int i = 0; i < 16; ++i) { O0[i] *= sc; O1[i] *= sc; }
  }
  const float mk = MR * AS;
#pragma unroll
  for (int i = 0; i < 16; ++i) {
    S0[i] = exp2f(__builtin_fmaf(S0[i], AS, -mk));
    S1[i] = exp2f(__builtin_fmaf(S1[i], AS, -mk));
  }
  float a[16];
#pragma unroll
  for (int i = 0; i < 16; ++i) a[i] = S0[i] + S1[i];
#pragma unroll
  for (int i = 0; i < 8; ++i) a[i] += a[i + 8];
#pragma unroll
  for (int i = 0; i < 4; ++i) a[i] += a[i + 4];
  LR += xhalf_sum((a[0] + a[1]) + (a[2] + a[3]));
  unsigned int W[2][4][2], X[2][4][2];
#pragma unroll
  for (int g = 0; g < 4; ++g)
#pragma unroll
    for (int c = 0; c < 2; ++c) {
      W[0][g][c] = cvtpk(S0[4 * g + 2 * c], S0[4 * g + 2 * c + 1]);
      W[1][g][c] = cvtpk(S1[4 * g + 2 * c], S1[4 * g + 2 * c + 1]);
    }
#pragma unroll
  for (int tt = 0; tt < 2; ++tt)
#pragma unroll
    for (int g = 0; g < 4; ++g)
#pragma unroll
      for (int c = 0; c < 2; ++c) X[tt][g][c] = __shfl_xor(W[tt][g][c], 32);

#pragma unroll
  for (int ks = 0; ks < 4; ++ks) {
    const int tt = ks >> 1, k1 = ks & 1;
    union { unsigned int d[4]; bf16x8 v; } u;
    u.d[0] = hi ? X[tt][2 * k1 + 1][0] : W[tt][2 * k1][0];
    u.d[1] = hi ? X[tt][2 * k1 + 1][1] : W[tt][2 * k1][1];
    u.d[2] = hi ? W[tt][2 * k1 + 1][0] : X[tt][2 * k1][0];
    u.d[3] = hi ? W[tt][2 * k1 + 1][1] : X[tt][2 * k1][1];
    Pf[ks] = u.v;
  }
}

__device__ __forceinline__ void write_o(unsigned short* Op, const f32x16& O0,
                                        const f32x16& O1, float LR, int hi) {
  const float inv = 1.0f / LR;
#pragma unroll
  for (int g = 0; g < 4; ++g) {
    unsigned int w00 = cvtpk(O0[4 * g] * inv, O0[4 * g + 1] * inv);
    unsigned int w01 = cvtpk(O0[4 * g + 2] * inv, O0[4 * g + 3] * inv);
    unsigned int w10 = cvtpk(O1[4 * g] * inv, O1[4 * g + 1] * inv);
    unsigned int w11 = cvtpk(O1[4 * g + 2] * inv, O1[4 * g + 3] * inv);
    const int dd = 8 * g + 4 * hi;
    *(uint2*)&Op[dd]      = uint2{w00, w01};
    *(uint2*)&Op[32 + dd] = uint2{w10, w11};
  }
}

// ---------------- causal flash attention, 1024 single-tile blocks ----------
// One 128-row q-tile per block (4 waves x 32 rows). Longest tiles first
// (qt = 15 - blk>>6) for LPT backfill; bh = blk&63 puts all 16 tiles of one
// bh on XCD bh%8 (K/V 512KB x 8 bh = 4MB = one L2). 4 blocks/CU -> 16 w/CU.
__global__ __launch_bounds__(256, 4) void attn_fwd(
    const unsigned short* __restrict__ Q, const unsigned short* __restrict__ K,
    const unsigned short* __restrict__ V, unsigned short* __restrict__ O) {
  __shared__ __align__(16) unsigned short Ks[64][72];  // [kv][hd]
  __shared__ __align__(16) unsigned short VT[64][72];  // [hd][kv]
  const int tid = threadIdx.x, lane = tid & 63, wv = tid >> 6;
  const int l31 = lane & 31, hi = lane >> 5;
  const int qt = 15 - (blockIdx.x >> 6);
  const int bh = blockIdx.x & 63;
  const int b = bh >> 4, h = bh & 15;
  const size_t bho = (size_t)(b * NUMH + h) * SEQL * HD;
  const unsigned short* Qb = Q + bho;
  const unsigned short* Kb = K + bho;
  const unsigned short* Vb = V + bho;

  const int q0w = qt * 128 + wv * 32;
  const int qrow = q0w + l31;

  const int skrow = tid >> 2, skcol = (tid & 3) * 16;
  const int svrow = tid & 63, svd = (tid >> 6) * 16;

  bf16x8 qf[4];
#pragma unroll
  for (int s = 0; s < 4; ++s)
    qf[s] = *(const bf16x8*)&Qb[(size_t)qrow * HD + s * 16 + hi * 8];

  f32x16 O0, O1;
#pragma unroll
  for (int i = 0; i < 16; ++i) { O0[i] = 0.f; O1[i] = 0.f; }
  float m_run = -1e30f, l_run = 0.f;

  const int nkt = 2 * qt + 2;
  for (int kt = 0; kt < nkt; ++kt) {
    const int ktb = kt * 64;
    __syncthreads();
    {  // stage K [64][64] -> Ks
      const unsigned short* kp = &Kb[(size_t)(ktb + skrow) * HD + skcol];
      *(uint4*)&Ks[skrow][skcol] = *(const uint4*)kp;
      *(uint4*)&Ks[skrow][skcol + 8] = *(const uint4*)(kp + 8);
    }
    {  // stage V transposed -> VT[d][kv]
      const unsigned short* vp = &Vb[(size_t)(ktb + svrow) * HD + svd];
      union { uint4 u[2]; unsigned short s[16]; } vb;
      vb.u[0] = *(const uint4*)vp;
      vb.u[1] = *(const uint4*)(vp + 8);
#pragma unroll
      for (int i = 0; i < 16; ++i) VT[svd + i][svrow] = vb.s[i];
    }
    __syncthreads();

    if (ktb <= q0w + 31) {  // wave-uniform participation
      f32x16 S0, S1;
#pragma unroll
      for (int i = 0; i < 16; ++i) { S0[i] = 0.f; S1[i] = 0.f; }
#pragma unroll
      for (int s = 0; s < 4; ++s) {
        bf16x8 kf0 = *(const bf16x8*)&Ks[l31][s * 16 + hi * 8];
        bf16x8 kf1 = *(const bf16x8*)&Ks[32 + l31][s * 16 + hi * 8];
        S0 = __builtin_amdgcn_mfma_f32_32x32x16_bf16(kf0, qf[s], S0, 0, 0, 0);
        S1 = __builtin_amdgcn_mfma_f32_32x32x16_bf16(kf1, qf[s], S1, 0, 0, 0);
      }
      bf16x8 Pf[4];
      sm_pack(S0, S1, m_run, l_run, O0, O1, Pf, ktb, qrow, q0w, hi);
#pragma unroll
      for (int ks = 0; ks < 4; ++ks) {
        bf16x8 vf0 = *(const bf16x8*)&VT[l31][ks * 16 + hi * 8];
        bf16x8 vf1 = *(const bf16x8*)&VT[32 + l31][ks * 16 + hi * 8];
        O0 = __builtin_amdgcn_mfma_f32_32x32x16_bf16(vf0, Pf[ks], O0, 0, 0, 0);
        O1 = __builtin_amdgcn_mfma_f32_32x32x16_bf16(vf1, Pf[ks], O1, 0, 0, 0);
      }
    }
  }

  write_o(O + ((size_t)b * SEQL + qrow) * EMB + h * HD, O0, O1, l_run, hi);
}

extern "C" void kernel_launch(void* const* d_in, const int* in_sizes, int n_in,
                              void* d_out, int out_size, void* d_ws, size_t ws_size,
                              hipStream_t stream) {
  const float* x     = (const float*)d_in[0];
  const float* w_qkv = (const float*)d_in[1];
  const float* b_qkv = (const float*)d_in[2];
  const float* w_out = (const float*)d_in[3];
  const float* b_out = (const float*)d_in[4];
  float* out = (float*)d_out;

  const size_t NE = (size_t)BATCH * NUMH * SEQL * HD;  // 8,388,608
  unsigned short* Qb = (unsigned short*)d_ws;
  unsigned short* Kb = Qb + NE;
  unsigned short* Vb = Kb + NE;
  unsigned short* AO = Vb + NE;
  unsigned short* xb = AO + NE;
  unsigned short* wqkvT = xb + NE;              // [3072][1024]
  unsigned short* woutT = wqkvT + 3072 * 1024;  // [1024][1024]

  cvt_x<<<dim3((unsigned)(NE / (256 * 8))), 256, 0, stream>>>(x, xb);
  tr_cvt<<<dim3(3072 / 32, 1024 / 32), 256, 0, stream>>>(w_qkv, wqkvT, 1024, 3072);
  tr_cvt<<<dim3(1024 / 32, 1024 / 32), 256, 0, stream>>>(w_out, woutT, 1024, 1024);

  gemm_qkv<<<dim3(1536), 256, 0, stream>>>(xb, wqkvT, b_qkv, Qb, Kb, Vb);
  attn_fwd<<<dim3(1024), 256, 0, stream>>>(Qb, Kb, Vb, AO);
  gemm_out<<<dim3(512), 256, 0, stream>>>(AO, woutT, b_out, out);
}

// Round 10
// 253.806 us; speedup vs baseline: 1.1731x; 1.0363x over previous
//
#include <hip/hip_runtime.h>
#include <hip/hip_bf16.h>

#define NUMH 16
#define HD   64
#define EMB  1024
#define SEQL 2048
#define BATCH 4

typedef __attribute__((ext_vector_type(8))) short bf16x8;
typedef __attribute__((ext_vector_type(4))) float f32x4;
typedef __attribute__((ext_vector_type(16))) float f32x16;

__device__ __forceinline__ unsigned short f2bf(float f) {
  union { float f; unsigned int u; } v; v.f = f;
  unsigned int u = v.u + 0x7fffu + ((v.u >> 16) & 1u);
  return (unsigned short)(u >> 16);
}

__device__ __forceinline__ unsigned int cvtpk(float lo, float hi) {
  unsigned int r;
  asm("v_cvt_pk_bf16_f32 %0, %1, %2" : "=v"(r) : "v"(lo), "v"(hi));
  return r;
}

// cross-half (lane ^ 32) merge — VERIFIED on HW in R8/R9 (absmax 0.0156).
__device__ __forceinline__ float xhalf_max(float x) {
#if __has_builtin(__builtin_amdgcn_permlane32_swap)
  auto r = __builtin_amdgcn_permlane32_swap(__float_as_uint(x), __float_as_uint(x), false, false);
  return fmaxf(__uint_as_float(r[0]), __uint_as_float(r[1]));
#else
  return fmaxf(x, __shfl_xor(x, 32));
#endif
}
__device__ __forceinline__ float xhalf_sum(float x) {
#if __has_builtin(__builtin_amdgcn_permlane32_swap)
  auto r = __builtin_amdgcn_permlane32_swap(__float_as_uint(x), __float_as_uint(x), false, false);
  return __uint_as_float(r[0]) + __uint_as_float(r[1]);
#else
  return x + __shfl_xor(x, 32);
#endif
}

#define GLOAD16(gp, lp)                                                        \
  __builtin_amdgcn_global_load_lds(                                            \
      (const __attribute__((address_space(1))) unsigned int*)(gp),             \
      (__attribute__((address_space(3))) unsigned int*)(lp), 16, 0, 0)

// ---------- convert x fp32 -> bf16 ----------
__global__ __launch_bounds__(256) void cvt_x(const float* __restrict__ src,
                                             unsigned short* __restrict__ dst) {
  const size_t i = ((size_t)blockIdx.x * 256 + threadIdx.x) * 8;
  float4 a = *(const float4*)(src + i);
  float4 b = *(const float4*)(src + i + 4);
  bf16x8 w;
  w[0]=(short)f2bf(a.x); w[1]=(short)f2bf(a.y); w[2]=(short)f2bf(a.z); w[3]=(short)f2bf(a.w);
  w[4]=(short)f2bf(b.x); w[5]=(short)f2bf(b.y); w[6]=(short)f2bf(b.z); w[7]=(short)f2bf(b.w);
  *(bf16x8*)(dst + i) = w;
}

// ---------- transpose + convert: src[R][C] fp32 -> dst[C][R] bf16 ----------
__global__ __launch_bounds__(256) void tr_cvt(const float* __restrict__ src,
                                              unsigned short* __restrict__ dst,
                                              int R, int C) {
  __shared__ unsigned short t[32][34];
  const int tx = threadIdx.x & 31, ty = threadIdx.x >> 5;
  const int c0 = blockIdx.x * 32, r0 = blockIdx.y * 32;
#pragma unroll
  for (int i = 0; i < 4; ++i)
    t[ty + i * 8][tx] = f2bf(src[(size_t)(r0 + ty + i * 8) * C + c0 + tx]);
  __syncthreads();
#pragma unroll
  for (int i = 0; i < 4; ++i)
    dst[(size_t)(c0 + ty + i * 8) * R + r0 + tx] = t[tx][ty + i * 8];
}

// ---------- GEMM, BK=64 + XOR-swizzled LDS (unchanged from R9) ----------
__global__ __launch_bounds__(256, 3) void gemm_qkv(
    const unsigned short* __restrict__ A, const unsigned short* __restrict__ BT,
    const float* __restrict__ Bias,
    unsigned short* __restrict__ Qo, unsigned short* __restrict__ Ko,
    unsigned short* __restrict__ Vo) {
  __shared__ __align__(16) unsigned short As[128][64];
  __shared__ __align__(16) unsigned short Bs[128][64];
  const int tid = threadIdx.x, lane = tid & 63, wv = tid >> 6;
  const int l15 = lane & 15, lg = lane >> 4;
  const int wrow = (wv >> 1) * 64, wcol = (wv & 1) * 64;
  const int cpx = gridDim.x >> 3;
  const int wg = (blockIdx.x & 7) * cpx + (blockIdx.x >> 3);
  const int mbase = (wg / 24) * 128, nbase = (wg % 24) * 128;

  f32x4 acc[4][4];
#pragma unroll
  for (int i = 0; i < 4; ++i)
#pragma unroll
    for (int j = 0; j < 4; ++j) acc[i][j] = (f32x4){0.f, 0.f, 0.f, 0.f};

  const int row0 = tid >> 3;
  const int scc = (tid & 7) ^ (row0 & 7);
  const unsigned short* gA0 = A + (size_t)(mbase + row0) * EMB + scc * 8;
  const unsigned short* gB0 = BT + (size_t)(nbase + row0) * EMB + scc * 8;
  unsigned short* lA0 = &As[0][0] + tid * 8;
  unsigned short* lB0 = &Bs[0][0] + tid * 8;

  for (int k0 = 0; k0 < EMB; k0 += 64) {
    __syncthreads();
#pragma unroll
    for (int i = 0; i < 4; ++i) {
      GLOAD16(gA0 + (size_t)(32 * i) * EMB + k0, lA0 + 2048 * i);
      GLOAD16(gB0 + (size_t)(32 * i) * EMB + k0, lB0 + 2048 * i);
    }
    __syncthreads();
#pragma unroll
    for (int ks2 = 0; ks2 < 2; ++ks2) {
      bf16x8 af[4], bfr[4];
      const int cc = ((ks2 * 4 + lg) ^ (l15 & 7)) * 8;
#pragma unroll
      for (int mf = 0; mf < 4; ++mf)
        af[mf] = *(const bf16x8*)&As[wrow + mf * 16 + l15][cc];
#pragma unroll
      for (int nf = 0; nf < 4; ++nf)
        bfr[nf] = *(const bf16x8*)&Bs[wcol + nf * 16 + l15][cc];
#pragma unroll
      for (int mf = 0; mf < 4; ++mf)
#pragma unroll
        for (int nf = 0; nf < 4; ++nf)
          acc[mf][nf] = __builtin_amdgcn_mfma_f32_16x16x32_bf16(af[mf], bfr[nf], acc[mf][nf], 0, 0, 0);
    }
  }

#pragma unroll
  for (int nf = 0; nf < 4; ++nf) {
    const int n = nbase + wcol + nf * 16 + l15;
    const float bias = Bias[n];
    const int which = n >> 10, rem = n & 1023;
    const int h = rem >> 6, d = rem & 63;
    unsigned short* dst = (which == 0) ? Qo : (which == 1) ? Ko : Vo;
#pragma unroll
    for (int mf = 0; mf < 4; ++mf)
#pragma unroll
      for (int j = 0; j < 4; ++j) {
        const int m = mbase + wrow + mf * 16 + lg * 4 + j;
        const int bb = m >> 11, s = m & 2047;
        dst[((size_t)(bb * NUMH + h) * SEQL + s) * HD + d] = f2bf(acc[mf][nf][j] + bias);
      }
  }
}

__global__ __launch_bounds__(256, 3) void gemm_out(
    const unsigned short* __restrict__ A, const unsigned short* __restrict__ BT,
    const float* __restrict__ Bias, float* __restrict__ Out) {
  __shared__ __align__(16) unsigned short As[128][64];
  __shared__ __align__(16) unsigned short Bs[128][64];
  const int tid = threadIdx.x, lane = tid & 63, wv = tid >> 6;
  const int l15 = lane & 15, lg = lane >> 4;
  const int wrow = (wv >> 1) * 64, wcol = (wv & 1) * 64;
  const int cpx = gridDim.x >> 3;
  const int wg = (blockIdx.x & 7) * cpx + (blockIdx.x >> 3);
  const int mbase = (wg >> 3) * 128, nbase = (wg & 7) * 128;

  f32x4 acc[4][4];
#pragma unroll
  for (int i = 0; i < 4; ++i)
#pragma unroll
    for (int j = 0; j < 4; ++j) acc[i][j] = (f32x4){0.f, 0.f, 0.f, 0.f};

  const int row0 = tid >> 3;
  const int scc = (tid & 7) ^ (row0 & 7);
  const unsigned short* gA0 = A + (size_t)(mbase + row0) * EMB + scc * 8;
  const unsigned short* gB0 = BT + (size_t)(nbase + row0) * EMB + scc * 8;
  unsigned short* lA0 = &As[0][0] + tid * 8;
  unsigned short* lB0 = &Bs[0][0] + tid * 8;

  for (int k0 = 0; k0 < EMB; k0 += 64) {
    __syncthreads();
#pragma unroll
    for (int i = 0; i < 4; ++i) {
      GLOAD16(gA0 + (size_t)(32 * i) * EMB + k0, lA0 + 2048 * i);
      GLOAD16(gB0 + (size_t)(32 * i) * EMB + k0, lB0 + 2048 * i);
    }
    __syncthreads();
#pragma unroll
    for (int ks2 = 0; ks2 < 2; ++ks2) {
      bf16x8 af[4], bfr[4];
      const int cc = ((ks2 * 4 + lg) ^ (l15 & 7)) * 8;
#pragma unroll
      for (int mf = 0; mf < 4; ++mf)
        af[mf] = *(const bf16x8*)&As[wrow + mf * 16 + l15][cc];
#pragma unroll
      for (int nf = 0; nf < 4; ++nf)
        bfr[nf] = *(const bf16x8*)&Bs[wcol + nf * 16 + l15][cc];
#pragma unroll
      for (int mf = 0; mf < 4; ++mf)
#pragma unroll
        for (int nf = 0; nf < 4; ++nf)
          acc[mf][nf] = __builtin_amdgcn_mfma_f32_16x16x32_bf16(af[mf], bfr[nf], acc[mf][nf], 0, 0, 0);
    }
  }

#pragma unroll
  for (int nf = 0; nf < 4; ++nf) {
    const int n = nbase + wcol + nf * 16 + l15;
    const float bias = Bias[n];
#pragma unroll
    for (int mf = 0; mf < 4; ++mf)
#pragma unroll
      for (int j = 0; j < 4; ++j) {
        const int m = mbase + wrow + mf * 16 + lg * 4 + j;
        Out[(size_t)m * EMB + n] = acc[mf][nf][j] + bias;
      }
  }
}

// ---- softmax + P-pack (HW-VERIFIED in R8/R9 — byte-identical) ----
__device__ __forceinline__ void sm_pack(f32x16& S0, f32x16& S1, float& MR, float& LR,
                                        f32x16& O0, f32x16& O1, bf16x8 Pf[4],
                                        int ktb, int qrow, int q0w, int hi) {
  const float AS = 0.18033688011112042f;  // 0.125 * log2(e)
  const float THRR = 44.36f;              // 8 / AS
  if (ktb + 63 > q0w) {
#pragma unroll
    for (int r = 0; r < 16; ++r) {
      const int kv0 = ktb + (r & 3) + 8 * (r >> 2) + 4 * hi;
      S0[r] = (kv0 > qrow) ? -1e30f : S0[r];
      S1[r] = (kv0 + 32 > qrow) ? -1e30f : S1[r];
    }
  }
  float t[16];
#pragma unroll
  for (int i = 0; i < 16; ++i) t[i] = fmaxf(S0[i], S1[i]);
#pragma unroll
  for (int i = 0; i < 8; ++i) t[i] = fmaxf(t[i], t[i + 8]);
#pragma unroll
  for (int i = 0; i < 4; ++i) t[i] = fmaxf(t[i], t[i + 4]);
  float mx = fmaxf(fmaxf(t[0], t[1]), fmaxf(t[2], t[3]));
  mx = xhalf_max(mx);
  if (!__all(mx - MR <= THRR)) {
    const float mn = fmaxf(MR, mx);
    const float sc = exp2f((MR - mn) * AS);
    MR = mn;
    LR *= sc;
#pragma unroll
    for (int i = 0; i < 16; ++i) { O0[i] *= sc; O1[i] *= sc; }
  }
  const float mk = MR * AS;
#pragma unroll
  for (int i = 0; i < 16; ++i) {
    S0[i] = exp2f(__builtin_fmaf(S0[i], AS, -mk));
    S1[i] = exp2f(__builtin_fmaf(S1[i], AS, -mk));
  }
  float a[16];
#pragma unroll
  for (int i = 0; i < 16; ++i) a[i] = S0[i] + S1[i];
#pragma unroll
  for (int i = 0; i < 8; ++i) a[i] += a[i + 8];
#pragma unroll
  for (int i = 0; i < 4; ++i) a[i] += a[i + 4];
  LR += xhalf_sum((a[0] + a[1]) + (a[2] + a[3]));
  unsigned int W[2][4][2], X[2][4][2];
#pragma unroll
  for (int g = 0; g < 4; ++g)
#pragma unroll
    for (int c = 0; c < 2; ++c) {
      W[0][g][c] = cvtpk(S0[4 * g + 2 * c], S0[4 * g + 2 * c + 1]);
      W[1][g][c] = cvtpk(S1[4 * g + 2 * c], S1[4 * g + 2 * c + 1]);
    }
#pragma unroll
  for (int tt = 0; tt < 2; ++tt)
#pragma unroll
    for (int g = 0; g < 4; ++g)
#pragma unroll
      for (int c = 0; c < 2; ++c) X[tt][g][c] = __shfl_xor(W[tt][g][c], 32);

#pragma unroll
  for (int ks = 0; ks < 4; ++ks) {
    const int tt = ks >> 1, k1 = ks & 1;
    union { unsigned int d[4]; bf16x8 v; } u;
    u.d[0] = hi ? X[tt][2 * k1 + 1][0] : W[tt][2 * k1][0];
    u.d[1] = hi ? X[tt][2 * k1 + 1][1] : W[tt][2 * k1][1];
    u.d[2] = hi ? W[tt][2 * k1 + 1][0] : X[tt][2 * k1][0];
    u.d[3] = hi ? W[tt][2 * k1 + 1][1] : X[tt][2 * k1][1];
    Pf[ks] = u.v;
  }
}

__device__ __forceinline__ void write_o(unsigned short* Op, const f32x16& O0,
                                        const f32x16& O1, float LR, int hi) {
  const float inv = 1.0f / LR;
#pragma unroll
  for (int g = 0; g < 4; ++g) {
    unsigned int w00 = cvtpk(O0[4 * g] * inv, O0[4 * g + 1] * inv);
    unsigned int w01 = cvtpk(O0[4 * g + 2] * inv, O0[4 * g + 3] * inv);
    unsigned int w10 = cvtpk(O1[4 * g] * inv, O1[4 * g + 1] * inv);
    unsigned int w11 = cvtpk(O1[4 * g + 2] * inv, O1[4 * g + 3] * inv);
    const int dd = 8 * g + 4 * hi;
    *(uint2*)&Op[dd]      = uint2{w00, w01};
    *(uint2*)&Op[32 + dd] = uint2{w10, w11};
  }
}

// ---------------- causal flash attention, 1024 blocks + T14 async staging ---
// T14: issue next-tile global loads (->regs) BEFORE compute; ds_write AFTER
// the post-compute barrier. HBM latency hides under QK/softmax/PV.
__global__ __launch_bounds__(256, 4) void attn_fwd(
    const unsigned short* __restrict__ Q, const unsigned short* __restrict__ K,
    const unsigned short* __restrict__ V, unsigned short* __restrict__ O) {
  __shared__ __align__(16) unsigned short Ks[64][72];  // [kv][hd]
  __shared__ __align__(16) unsigned short VT[64][72];  // [hd][kv]
  const int tid = threadIdx.x, lane = tid & 63, wv = tid >> 6;
  const int l31 = lane & 31, hi = lane >> 5;
  const int qt = 15 - (blockIdx.x >> 6);
  const int bh = blockIdx.x & 63;
  const int b = bh >> 4, h = bh & 15;
  const size_t bho = (size_t)(b * NUMH + h) * SEQL * HD;
  const unsigned short* Qb = Q + bho;
  const unsigned short* Kb = K + bho;
  const unsigned short* Vb = V + bho;

  const int q0w = qt * 128 + wv * 32;
  const int qrow = q0w + l31;

  const int skrow = tid >> 2, skcol = (tid & 3) * 16;
  const int svrow = tid & 63, svd = (tid >> 6) * 16;
  const unsigned short* kbase = &Kb[(size_t)skrow * HD + skcol];
  const unsigned short* vbase = &Vb[(size_t)svrow * HD + svd];

  bf16x8 qf[4];
#pragma unroll
  for (int s = 0; s < 4; ++s)
    qf[s] = *(const bf16x8*)&Qb[(size_t)qrow * HD + s * 16 + hi * 8];

  f32x16 O0, O1;
#pragma unroll
  for (int i = 0; i < 16; ++i) { O0[i] = 0.f; O1[i] = 0.f; }
  float m_run = -1e30f, l_run = 0.f;

  const int nkt = 2 * qt + 2;

  // prologue: stage tile 0
  {
    uint4 k0 = *(const uint4*)kbase;
    uint4 k1 = *(const uint4*)(kbase + 8);
    uint4 v0 = *(const uint4*)vbase;
    uint4 v1 = *(const uint4*)(vbase + 8);
    *(uint4*)&Ks[skrow][skcol] = k0;
    *(uint4*)&Ks[skrow][skcol + 8] = k1;
    union { uint4 u[2]; unsigned short s[16]; } vb;
    vb.u[0] = v0; vb.u[1] = v1;
#pragma unroll
    for (int i = 0; i < 16; ++i) VT[svd + i][svrow] = vb.s[i];
  }
  __syncthreads();

  for (int kt = 0; kt < nkt; ++kt) {
    const int ktb = kt * 64;
    const bool more = (kt + 1 < nkt);
    // ---- T14 issue-early: global loads for tile kt+1 into registers ----
    uint4 kr0, kr1, vr0, vr1;
    if (more) {
      const unsigned short* kp = kbase + (size_t)(ktb + 64) * HD;
      const unsigned short* vp = vbase + (size_t)(ktb + 64) * HD;
      kr0 = *(const uint4*)kp;
      kr1 = *(const uint4*)(kp + 8);
      vr0 = *(const uint4*)vp;
      vr1 = *(const uint4*)(vp + 8);
    }
    // ---- compute tile kt from LDS ----
    if (ktb <= q0w + 31) {
      f32x16 S0, S1;
#pragma unroll
      for (int i = 0; i < 16; ++i) { S0[i] = 0.f; S1[i] = 0.f; }
#pragma unroll
      for (int s = 0; s < 4; ++s) {
        bf16x8 kf0 = *(const bf16x8*)&Ks[l31][s * 16 + hi * 8];
        bf16x8 kf1 = *(const bf16x8*)&Ks[32 + l31][s * 16 + hi * 8];
        S0 = __builtin_amdgcn_mfma_f32_32x32x16_bf16(kf0, qf[s], S0, 0, 0, 0);
        S1 = __builtin_amdgcn_mfma_f32_32x32x16_bf16(kf1, qf[s], S1, 0, 0, 0);
      }
      bf16x8 Pf[4];
      sm_pack(S0, S1, m_run, l_run, O0, O1, Pf, ktb, qrow, q0w, hi);
#pragma unroll
      for (int ks = 0; ks < 4; ++ks) {
        bf16x8 vf0 = *(const bf16x8*)&VT[l31][ks * 16 + hi * 8];
        bf16x8 vf1 = *(const bf16x8*)&VT[32 + l31][ks * 16 + hi * 8];
        O0 = __builtin_amdgcn_mfma_f32_32x32x16_bf16(vf0, Pf[ks], O0, 0, 0, 0);
        O1 = __builtin_amdgcn_mfma_f32_32x32x16_bf16(vf1, Pf[ks], O1, 0, 0, 0);
      }
    }
    __syncthreads();  // all waves done reading Ks/VT for tile kt
    // ---- T14 write-late: regs -> LDS for tile kt+1 ----
    if (more) {
      *(uint4*)&Ks[skrow][skcol] = kr0;
      *(uint4*)&Ks[skrow][skcol + 8] = kr1;
      union { uint4 u[2]; unsigned short s[16]; } vb;
      vb.u[0] = vr0; vb.u[1] = vr1;
#pragma unroll
      for (int i = 0; i < 16; ++i) VT[svd + i][svrow] = vb.s[i];
    }
    __syncthreads();  // writes visible before next compute
  }

  write_o(O + ((size_t)b * SEQL + qrow) * EMB + h * HD, O0, O1, l_run, hi);
}

extern "C" void kernel_launch(void* const* d_in, const int* in_sizes, int n_in,
                              void* d_out, int out_size, void* d_ws, size_t ws_size,
                              hipStream_t stream) {
  const float* x     = (const float*)d_in[0];
  const float* w_qkv = (const float*)d_in[1];
  const float* b_qkv = (const float*)d_in[2];
  const float* w_out = (const float*)d_in[3];
  const float* b_out = (const float*)d_in[4];
  float* out = (float*)d_out;

  const size_t NE = (size_t)BATCH * NUMH * SEQL * HD;  // 8,388,608
  unsigned short* Qb = (unsigned short*)d_ws;
  unsigned short* Kb = Qb + NE;
  unsigned short* Vb = Kb + NE;
  unsigned short* AO = Vb + NE;
  unsigned short* xb = AO + NE;
  unsigned short* wqkvT = xb + NE;              // [3072][1024]
  unsigned short* woutT = wqkvT + 3072 * 1024;  // [1024][1024]

  cvt_x<<<dim3((unsigned)(NE / (256 * 8))), 256, 0, stream>>>(x, xb);
  tr_cvt<<<dim3(3072 / 32, 1024 / 32), 256, 0, stream>>>(w_qkv, wqkvT, 1024, 3072);
  tr_cvt<<<dim3(1024 / 32, 1024 / 32), 256, 0, stream>>>(w_out, woutT, 1024, 1024);

  gemm_qkv<<<dim3(1536), 256, 0, stream>>>(xb, wqkvT, b_qkv, Qb, Kb, Vb);
  attn_fwd<<<dim3(1024), 256, 0, stream>>>(Qb, Kb, Vb, AO);
  gemm_out<<<dim3(512), 256, 0, stream>>>(AO, woutT, b_out, out);
}